// Round 5
// baseline (676.110 us; speedup 1.0000x reference)
//
#include <hip/hip_runtime.h>

#define N_NODES 50000
#define N_EDGES 800000
#define N_GRAPHS 256
#define HIDDEN 128
#define N_LAYERS 5
#define OUT_DIM 10
#define BN_EPS 1e-5f

#define BUCKET_SHIFT 7
#define BUCKET_NODES 128
#define N_BUCKETS ((N_NODES + BUCKET_NODES - 1) / BUCKET_NODES)  // 391
#define STAGE_THREADS 1024
#define STAGE_EPB 4096  // edges per block

typedef __bf16 bf16x8 __attribute__((ext_vector_type(8)));
typedef float f32x4 __attribute__((ext_vector_type(4)));

union FragAB {
    bf16x8 v;
    ushort s[8];
    uint4 q;
};

__device__ inline float bf2f(ushort u) {
    union { uint i; float f; } v;
    v.i = ((uint)u) << 16;
    return v.f;
}

__device__ inline float bf2f_lo(uint u) {
    union { uint i; float f; } v;
    v.i = u << 16;
    return v.f;
}

__device__ inline float bf2f_hi(uint u) {
    union { uint i; float f; } v;
    v.i = u & 0xffff0000u;
    return v.f;
}

__device__ inline ushort f2bf(float f) {
    union { float f; uint u; } v;
    v.f = f;
    uint b = v.u;
    uint r = (b + 0x7fffu + ((b >> 16) & 1u)) >> 16;  // RNE
    return (ushort)r;
}

// ---------------- CSR build ----------------

__global__ void k_hist(const int* __restrict__ dst, int* __restrict__ counts) {
    int e = blockIdx.x * blockDim.x + threadIdx.x;
    if (e < N_EDGES) atomicAdd(&counts[dst[e]], 1);
}

__global__ void k_scan_blocks(const int* __restrict__ in, int* __restrict__ out,
                              int* __restrict__ bsum, int n) {
    __shared__ int s[256];
    int i = blockIdx.x * 256 + threadIdx.x;
    int v = (i < n) ? in[i] : 0;
    s[threadIdx.x] = v;
    __syncthreads();
    for (int off = 1; off < 256; off <<= 1) {
        int t = (threadIdx.x >= off) ? s[threadIdx.x - off] : 0;
        __syncthreads();
        s[threadIdx.x] += t;
        __syncthreads();
    }
    if (i < n) out[i] = s[threadIdx.x];
    if (threadIdx.x == 255) bsum[blockIdx.x] = s[255];
}

__global__ void k_scan_sums(int* __restrict__ bsum, int nb) {
    __shared__ int s[256];
    int t = threadIdx.x;
    int v = (t < nb) ? bsum[t] : 0;
    s[t] = v;
    __syncthreads();
    for (int off = 1; off < 256; off <<= 1) {
        int tv = (t >= off) ? s[t - off] : 0;
        __syncthreads();
        s[t] += tv;
        __syncthreads();
    }
    int excl = (t == 0) ? 0 : s[t - 1];
    if (t < nb) bsum[t] = excl;
}

__global__ void k_offsets(const int* __restrict__ scanned, const int* __restrict__ boff,
                          int* __restrict__ offsets, int n) {
    int i = blockIdx.x * 256 + threadIdx.x;
    if (i < n) offsets[i + 1] = scanned[i] + boff[blockIdx.x];
    if (i == 0) offsets[0] = 0;
}

__global__ void k_bcur(const int* __restrict__ offsets, int* __restrict__ bcur) {
    int b = blockIdx.x * 256 + threadIdx.x;
    if (b < N_BUCKETS) bcur[b] = offsets[b * BUCKET_NODES];
}

// pass A: block-local LDS binning into dst-bucket-ordered packed staging.
__global__ __launch_bounds__(STAGE_THREADS) void k_stage(const int* __restrict__ esrc,
                                                         const int* __restrict__ edst,
                                                         int* __restrict__ bcur,
                                                         uint* __restrict__ stage) {
    __shared__ int lcnt[N_BUCKETS];
    __shared__ int lbase[N_BUCKETS];
    int tid = threadIdx.x;
    for (int i = tid; i < N_BUCKETS; i += STAGE_THREADS) lcnt[i] = 0;
    __syncthreads();
    int e0 = blockIdx.x * STAGE_EPB;
    uint pk[4];
    int bk[4];
    bool val[4];
#pragma unroll
    for (int i = 0; i < 4; ++i) {
        int e = e0 + i * STAGE_THREADS + tid;
        val[i] = e < N_EDGES;
        bk[i] = 0;
        pk[i] = 0;
        if (val[i]) {
            int d = edst[e];
            int s = esrc[e];
            bk[i] = d >> BUCKET_SHIFT;
            pk[i] = (uint)s | ((uint)(d & (BUCKET_NODES - 1)) << 16);
            atomicAdd(&lcnt[bk[i]], 1);
        }
    }
    __syncthreads();
    for (int i = tid; i < N_BUCKETS; i += STAGE_THREADS) {
        int c = lcnt[i];
        lbase[i] = c ? atomicAdd(&bcur[i], c) : 0;
        lcnt[i] = 0;
    }
    __syncthreads();
#pragma unroll
    for (int i = 0; i < 4; ++i) {
        if (val[i]) {
            int off = atomicAdd(&lcnt[bk[i]], 1);
            stage[lbase[bk[i]] + off] = pk[i];
        }
    }
}

// pass B: per-bucket local scatter into final adj via LDS cursors
__global__ __launch_bounds__(256) void k_fill2(const uint* __restrict__ stage,
                                               const int* __restrict__ offsets,
                                               ushort* __restrict__ adj) {
    __shared__ int lcur[BUCKET_NODES];
    int bk = blockIdx.x;
    int n0 = bk * BUCKET_NODES;
    int n1 = n0 + BUCKET_NODES;
    if (n1 > N_NODES) n1 = N_NODES;
    int cnt = n1 - n0;
    if ((int)threadIdx.x < cnt) lcur[threadIdx.x] = offsets[n0 + threadIdx.x];
    __syncthreads();
    int s = offsets[n0];
    int e = offsets[n1];
    for (int i = s + threadIdx.x; i < e; i += 256) {
        uint pk = stage[i];
        int dl = pk >> 16;
        int pos = atomicAdd(&lcur[dl], 1);
        adj[pos] = (ushort)(pk & 0xffffu);
    }
}

// ---------------- fp32 -> bf16 convert ----------------

__global__ __launch_bounds__(256) void k_cvt(const float* __restrict__ x,
                                             ushort* __restrict__ xb, int n4) {
    int i = blockIdx.x * 256 + threadIdx.x;
    if (i < n4) {
        float4 v = ((const float4*)x)[i];
        ushort4 o;
        o.x = f2bf(v.x); o.y = f2bf(v.y); o.z = f2bf(v.z); o.w = f2bf(v.w);
        ((ushort4*)xb)[i] = o;
    }
}

// ---------------- pack W into MFMA-B fragment order ----------------

__global__ __launch_bounds__(256) void k_pack_w(const float* __restrict__ W1,
                                                const float* __restrict__ W2,
                                                ushort* __restrict__ Wp) {
    int mat = blockIdx.x;  // 0..9
    const float* src = (mat < 5) ? (W1 + (size_t)mat * 16384)
                                 : (W2 + (size_t)(mat - 5) * 16384);
    ushort* dst = Wp + (size_t)mat * 16384;
    for (int idx = threadIdx.x; idx < 16384; idx += 256) {
        int jj = idx & 7;
        int frag = idx >> 3;
        int lane = frag & 63;
        int cf = frag >> 6;
        int ct = cf >> 2, kc = cf & 3;
        int k = kc * 32 + (lane >> 4) * 8 + jj;
        int c = ct * 16 + (lane & 15);
        dst[idx] = f2bf(src[k * 128 + c]);
    }
}

// ---------------- fused aggregation + GEMM1 + stats ----------------
// Per block: 64 output rows. Gather phase: wave w handles rows w*16..+15; for each
// row, 16 lanes x uint4 cover the 256B feature row, lane-group e=lane>>4 covers
// edge j+e (4 edges per load, 2x unrolled). Reduce via shfl_xor, add self, store
// A-tile to swizzled LDS. Then MFMA Z1 = A @ W1 + b1 with fused column stats.

__global__ __launch_bounds__(256) void k_agg_gemm1(const ushort* __restrict__ h,
                                                   const int* __restrict__ offsets,
                                                   const ushort* __restrict__ adj,
                                                   const ushort* __restrict__ Wp,
                                                   const float* __restrict__ bias,
                                                   ushort* __restrict__ Z,
                                                   float* __restrict__ statOut) {
    __shared__ ushort As[64 * 128];  // swizzled A tile / reused as output tile
    __shared__ float redS[4][128];
    __shared__ float redQ[4][128];

    int tid = threadIdx.x;
    int w = tid >> 6, lane = tid & 63;
    int e = lane >> 4, c16 = lane & 15;
    int r0 = blockIdx.x * 64;
    const uint4* h4 = (const uint4*)h;

    // ---- gather phase ----
    for (int i = 0; i < 16; ++i) {
        int rl = w * 16 + i;
        int r = r0 + rl;
        float a0 = 0.f, a1 = 0.f, a2 = 0.f, a3 = 0.f;
        float a4 = 0.f, a5 = 0.f, a6 = 0.f, a7 = 0.f;
        if (r < N_NODES) {
            int off = offsets[r];
            int end = offsets[r + 1];
            int j = off;
            for (; j + 8 <= end; j += 8) {
                int u0 = adj[j + e];
                int u1 = adj[j + 4 + e];
                uint4 t0 = h4[(size_t)u0 * 16 + c16];
                uint4 t1 = h4[(size_t)u1 * 16 + c16];
                a0 += bf2f_lo(t0.x); a1 += bf2f_hi(t0.x);
                a2 += bf2f_lo(t0.y); a3 += bf2f_hi(t0.y);
                a4 += bf2f_lo(t0.z); a5 += bf2f_hi(t0.z);
                a6 += bf2f_lo(t0.w); a7 += bf2f_hi(t0.w);
                a0 += bf2f_lo(t1.x); a1 += bf2f_hi(t1.x);
                a2 += bf2f_lo(t1.y); a3 += bf2f_hi(t1.y);
                a4 += bf2f_lo(t1.z); a5 += bf2f_hi(t1.z);
                a6 += bf2f_lo(t1.w); a7 += bf2f_hi(t1.w);
            }
            for (; j < end; j += 4) {
                bool valid = (j + e) < end;
                int u = valid ? adj[j + e] : 0;
                uint4 t = valid ? h4[(size_t)u * 16 + c16] : make_uint4(0, 0, 0, 0);
                a0 += bf2f_lo(t.x); a1 += bf2f_hi(t.x);
                a2 += bf2f_lo(t.y); a3 += bf2f_hi(t.y);
                a4 += bf2f_lo(t.z); a5 += bf2f_hi(t.z);
                a6 += bf2f_lo(t.w); a7 += bf2f_hi(t.w);
            }
        }
        a0 += __shfl_xor(a0, 16, 64); a0 += __shfl_xor(a0, 32, 64);
        a1 += __shfl_xor(a1, 16, 64); a1 += __shfl_xor(a1, 32, 64);
        a2 += __shfl_xor(a2, 16, 64); a2 += __shfl_xor(a2, 32, 64);
        a3 += __shfl_xor(a3, 16, 64); a3 += __shfl_xor(a3, 32, 64);
        a4 += __shfl_xor(a4, 16, 64); a4 += __shfl_xor(a4, 32, 64);
        a5 += __shfl_xor(a5, 16, 64); a5 += __shfl_xor(a5, 32, 64);
        a6 += __shfl_xor(a6, 16, 64); a6 += __shfl_xor(a6, 32, 64);
        a7 += __shfl_xor(a7, 16, 64); a7 += __shfl_xor(a7, 32, 64);
        if (e == 0) {
            uint4 pk = make_uint4(0, 0, 0, 0);
            if (r < N_NODES) {
                uint4 self = h4[(size_t)r * 16 + c16];
                a0 += bf2f_lo(self.x); a1 += bf2f_hi(self.x);
                a2 += bf2f_lo(self.y); a3 += bf2f_hi(self.y);
                a4 += bf2f_lo(self.z); a5 += bf2f_hi(self.z);
                a6 += bf2f_lo(self.w); a7 += bf2f_hi(self.w);
                pk.x = (uint)f2bf(a0) | ((uint)f2bf(a1) << 16);
                pk.y = (uint)f2bf(a2) | ((uint)f2bf(a3) << 16);
                pk.z = (uint)f2bf(a4) | ((uint)f2bf(a5) << 16);
                pk.w = (uint)f2bf(a6) | ((uint)f2bf(a7) << 16);
            }
            *(uint4*)(As + rl * 128 + (((c16 + rl) & 15) * 8)) = pk;
        }
    }
    __syncthreads();

    // ---- MFMA phase ----
    int m = lane & 15, quad = lane >> 4;
    f32x4 acc[8];
#pragma unroll
    for (int ct = 0; ct < 8; ++ct) acc[ct] = (f32x4){0.f, 0.f, 0.f, 0.f};

    const uint4* Wp4 = (const uint4*)Wp;
    int arow = w * 16 + m;

#pragma unroll
    for (int kc = 0; kc < 4; ++kc) {
        FragAB a;
        int ch = kc * 4 + quad;
        a.q = *(const uint4*)(As + arow * 128 + (((ch + arow) & 15) * 8));
#pragma unroll
        for (int ct = 0; ct < 8; ++ct) {
            FragAB bf;
            bf.q = Wp4[(ct * 4 + kc) * 64 + lane];
            acc[ct] = __builtin_amdgcn_mfma_f32_16x16x32_bf16(a.v, bf.v, acc[ct], 0, 0, 0);
        }
    }
    __syncthreads();  // done reading As; reuse as output tile

    int rbase = w * 16 + quad * 4;
#pragma unroll
    for (int ct = 0; ct < 8; ++ct) {
        int c = ct * 16 + m;
        float bc = bias[c];
        float s = 0.f, s2 = 0.f;
#pragma unroll
        for (int i = 0; i < 4; ++i) {
            float val = acc[ct][i] + bc;
            As[(rbase + i) * 128 + c] = f2bf(val);
            if (r0 + rbase + i < N_NODES) {
                s += val;
                s2 += val * val;
            }
        }
        s += __shfl_xor(s, 16, 64);
        s += __shfl_xor(s, 32, 64);
        s2 += __shfl_xor(s2, 16, 64);
        s2 += __shfl_xor(s2, 32, 64);
        if (quad == 0) {
            redS[w][c] = s;
            redQ[w][c] = s2;
        }
    }
    __syncthreads();

#pragma unroll
    for (int it = 0; it < 4; ++it) {
        int id = tid + it * 256;
        int row = id >> 4, seg = id & 15;
        int gr = r0 + row;
        if (gr < N_NODES)
            *(uint4*)(Z + (size_t)gr * 128 + seg * 8) = *(const uint4*)(As + row * 128 + seg * 8);
    }
    if (tid < 128) {
        float s = redS[0][tid] + redS[1][tid] + redS[2][tid] + redS[3][tid];
        float q = redQ[0][tid] + redQ[1][tid] + redQ[2][tid] + redQ[3][tid];
        int slot = (blockIdx.x & 7) * 256;
        atomicAdd(&statOut[slot + tid], s);
        atomicAdd(&statOut[slot + 128 + tid], q);
    }
}

// ---------------- MFMA GEMM2 (BN1+ReLU on input) + stats ----------------

__global__ __launch_bounds__(256) void k_gemm2(const ushort* __restrict__ A,
                                               const ushort* __restrict__ Wp,
                                               const float* __restrict__ bias,
                                               const float* __restrict__ g,
                                               const float* __restrict__ b,
                                               const float* __restrict__ statIn,
                                               ushort* __restrict__ Z,
                                               float* __restrict__ statOut) {
    __shared__ ushort As[64 * 128];
    __shared__ float scs[128];
    __shared__ float shs[128];
    __shared__ float redS[4][128];
    __shared__ float redQ[4][128];

    int tid = threadIdx.x;
    int r0 = blockIdx.x * 64;

    if (tid < 128) {
        float s = 0.f, q = 0.f;
#pragma unroll
        for (int sl = 0; sl < 8; ++sl) {
            s += statIn[sl * 256 + tid];
            q += statIn[sl * 256 + 128 + tid];
        }
        float mn = s * (1.f / N_NODES);
        float var = q * (1.f / N_NODES) - mn * mn;
        float sc = g[tid] * rsqrtf(var + BN_EPS);
        scs[tid] = sc;
        shs[tid] = b[tid] - mn * sc;
    }
    __syncthreads();

#pragma unroll
    for (int it = 0; it < 4; ++it) {
        int id = tid + it * 256;
        int row = id >> 4, ch = id & 15;
        int gr = r0 + row;
        uint4 v = make_uint4(0, 0, 0, 0);
        if (gr < N_NODES) {
            v = *(const uint4*)(A + (size_t)gr * 128 + ch * 8);
            FragAB f;
            f.q = v;
            int c0 = ch * 8;
#pragma unroll
            for (int j = 0; j < 8; ++j) {
                float fv = bf2f(f.s[j]);
                fv = fmaxf(fv * scs[c0 + j] + shs[c0 + j], 0.f);
                f.s[j] = f2bf(fv);
            }
            v = f.q;
        }
        *(uint4*)(As + row * 128 + (((ch + row) & 15) * 8)) = v;
    }
    __syncthreads();

    int w = tid >> 6, lane = tid & 63;
    int m = lane & 15, quad = lane >> 4;

    f32x4 acc[8];
#pragma unroll
    for (int ct = 0; ct < 8; ++ct) acc[ct] = (f32x4){0.f, 0.f, 0.f, 0.f};

    const uint4* Wp4 = (const uint4*)Wp;
    int arow = w * 16 + m;

#pragma unroll
    for (int kc = 0; kc < 4; ++kc) {
        FragAB a;
        int ch = kc * 4 + quad;
        a.q = *(const uint4*)(As + arow * 128 + (((ch + arow) & 15) * 8));
#pragma unroll
        for (int ct = 0; ct < 8; ++ct) {
            FragAB bf;
            bf.q = Wp4[(ct * 4 + kc) * 64 + lane];
            acc[ct] = __builtin_amdgcn_mfma_f32_16x16x32_bf16(a.v, bf.v, acc[ct], 0, 0, 0);
        }
    }
    __syncthreads();

    int rbase = w * 16 + quad * 4;
#pragma unroll
    for (int ct = 0; ct < 8; ++ct) {
        int c = ct * 16 + m;
        float bc = bias[c];
        float s = 0.f, s2 = 0.f;
#pragma unroll
        for (int i = 0; i < 4; ++i) {
            float val = acc[ct][i] + bc;
            As[(rbase + i) * 128 + c] = f2bf(val);
            if (r0 + rbase + i < N_NODES) {
                s += val;
                s2 += val * val;
            }
        }
        s += __shfl_xor(s, 16, 64);
        s += __shfl_xor(s, 32, 64);
        s2 += __shfl_xor(s2, 16, 64);
        s2 += __shfl_xor(s2, 32, 64);
        if (quad == 0) {
            redS[w][c] = s;
            redQ[w][c] = s2;
        }
    }
    __syncthreads();

#pragma unroll
    for (int it = 0; it < 4; ++it) {
        int id = tid + it * 256;
        int row = id >> 4, seg = id & 15;
        int gr = r0 + row;
        if (gr < N_NODES)
            *(uint4*)(Z + (size_t)gr * 128 + seg * 8) = *(const uint4*)(As + row * 128 + seg * 8);
    }
    if (tid < 128) {
        float s = redS[0][tid] + redS[1][tid] + redS[2][tid] + redS[3][tid];
        float q = redQ[0][tid] + redQ[1][tid] + redQ[2][tid] + redQ[3][tid];
        int slot = (blockIdx.x & 7) * 256;
        atomicAdd(&statOut[slot + tid], s);
        atomicAdd(&statOut[slot + 128 + tid], q);
    }
}

// ---------------- BN2+ReLU + h write + segment pool (wave per 64 rows) ----------------

__global__ __launch_bounds__(256) void k_apply_pool(const ushort* __restrict__ z2,
                                                    const float* __restrict__ statIn,
                                                    const float* __restrict__ g,
                                                    const float* __restrict__ b,
                                                    const int* __restrict__ batch,
                                                    ushort* __restrict__ h,
                                                    float* __restrict__ pooled) {
    int w = threadIdx.x >> 6, lane = threadIdx.x & 63;
    int c0 = lane * 2;
    float s0 = 0.f, q0 = 0.f, s1 = 0.f, q1 = 0.f;
#pragma unroll
    for (int sl = 0; sl < 8; ++sl) {
        s0 += statIn[sl * 256 + c0];
        q0 += statIn[sl * 256 + 128 + c0];
        s1 += statIn[sl * 256 + c0 + 1];
        q1 += statIn[sl * 256 + 128 + c0 + 1];
    }
    float mn0 = s0 * (1.f / N_NODES);
    float var0 = q0 * (1.f / N_NODES) - mn0 * mn0;
    float sc0 = g[c0] * rsqrtf(var0 + BN_EPS);
    float sh0 = b[c0] - mn0 * sc0;
    float mn1 = s1 * (1.f / N_NODES);
    float var1 = q1 * (1.f / N_NODES) - mn1 * mn1;
    float sc1 = g[c0 + 1] * rsqrtf(var1 + BN_EPS);
    float sh1 = b[c0 + 1] - mn1 * sc1;

    int r0 = blockIdx.x * 256 + w * 64;
    int r1 = r0 + 64;
    if (r1 > N_NODES) r1 = N_NODES;
    if (r0 >= N_NODES) return;

    int bidx = r0 + lane;
    int myb = batch[bidx < N_NODES ? bidx : (N_NODES - 1)];

    float a0 = 0.f, a1 = 0.f;
    int curg = -1;
    const uint* z1 = (const uint*)z2;
    uint* h1 = (uint*)h;
    for (int r = r0; r < r1; ++r) {
        uint t = z1[(size_t)r * 64 + lane];
        float v0 = fmaxf(bf2f((ushort)(t & 0xffff)) * sc0 + sh0, 0.f);
        float v1 = fmaxf(bf2f((ushort)(t >> 16)) * sc1 + sh1, 0.f);
        h1[(size_t)r * 64 + lane] = (uint)f2bf(v0) | ((uint)f2bf(v1) << 16);
        int gg = __shfl(myb, r - r0, 64);
        if (gg != curg) {
            if (curg >= 0) {
                atomicAdd(&pooled[(size_t)curg * 640 + c0], a0);
                atomicAdd(&pooled[(size_t)curg * 640 + c0 + 1], a1);
            }
            a0 = 0.f; a1 = 0.f;
            curg = gg;
        }
        a0 += v0;
        a1 += v1;
    }
    if (curg >= 0) {
        atomicAdd(&pooled[(size_t)curg * 640 + c0], a0);
        atomicAdd(&pooled[(size_t)curg * 640 + c0 + 1], a1);
    }
}

// ---------------- final MLP ----------------

__global__ __launch_bounds__(128) void k_mlp(const float* __restrict__ pooled,
                                             const float* __restrict__ fc1W,
                                             const float* __restrict__ fc1b,
                                             const float* __restrict__ fc2W,
                                             const float* __restrict__ fc2b,
                                             float* __restrict__ out) {
    __shared__ float p[640];
    __shared__ float hid[128];
    int g = blockIdx.x;
    int t = threadIdx.x;
    for (int i = t; i < 640; i += 128) p[i] = pooled[(size_t)g * 640 + i];
    __syncthreads();
    float a = fc1b[t];
    for (int k = 0; k < 640; ++k) a += p[k] * fc1W[(size_t)k * 128 + t];
    hid[t] = fmaxf(a, 0.f);
    __syncthreads();
    if (t < OUT_DIM) {
        float o = fc2b[t];
#pragma unroll 8
        for (int c = 0; c < 128; ++c) o += hid[c] * fc2W[(size_t)c * OUT_DIM + t];
        out[(size_t)g * OUT_DIM + t] = o;
    }
}

// ---------------- host ----------------

static inline char* align256(char* p) {
    return (char*)(((uintptr_t)p + 255) & ~(uintptr_t)255);
}

extern "C" void kernel_launch(void* const* d_in, const int* in_sizes, int n_in,
                              void* d_out, int out_size, void* d_ws, size_t ws_size,
                              hipStream_t stream) {
    const float* x    = (const float*)d_in[0];
    const float* W1   = (const float*)d_in[1];
    const float* b1   = (const float*)d_in[2];
    const float* bng1 = (const float*)d_in[3];
    const float* bnb1 = (const float*)d_in[4];
    const float* W2   = (const float*)d_in[5];
    const float* b2   = (const float*)d_in[6];
    const float* bng2 = (const float*)d_in[7];
    const float* bnb2 = (const float*)d_in[8];
    const float* fc1W = (const float*)d_in[9];
    const float* fc1b = (const float*)d_in[10];
    const float* fc2W = (const float*)d_in[11];
    const float* fc2b = (const float*)d_in[12];
    const int* ei     = (const int*)d_in[13];
    const int* batch  = (const int*)d_in[14];
    const int* esrc = ei;
    const int* edst = ei + N_EDGES;

    const size_t NF = (size_t)N_NODES * HIDDEN;
    char* p = (char*)d_ws;
    ushort* z2bf = (ushort*)p; p = align256(p + NF * 2);
    ushort* z1bf = (ushort*)p; p = align256(p + NF * 2);
    ushort* hbf  = (ushort*)p; p = align256(p + NF * 2);
    ushort* xbf  = (ushort*)p; p = align256(p + NF * 2);
    ushort* Wp   = (ushort*)p; p = align256(p + (size_t)10 * 16384 * 2);
    float* pooled = (float*)p; p += (size_t)N_GRAPHS * 640 * 4;
    float* stats  = (float*)p; p = align256(p + (size_t)10 * 8 * 256 * 4);
    int* counts   = (int*)p; p = align256(p + (size_t)N_NODES * 4);
    int* offsets  = (int*)p; p = align256(p + (size_t)(N_NODES + 1) * 4);
    int* bcur     = (int*)p; p = align256(p + (size_t)N_BUCKETS * 4);
    int* bsum     = (int*)p; p = align256(p + 256 * 4);
    ushort* adj   = (ushort*)p; p = align256(p + (size_t)N_EDGES * 2);
    uint* stage   = (uint*)p; p = align256(p + (size_t)N_EDGES * 4);

    hipMemsetAsync(counts, 0, (size_t)N_NODES * 4, stream);
    hipMemsetAsync(pooled, 0, ((size_t)N_GRAPHS * 640 + (size_t)10 * 8 * 256) * 4, stream);

    const int SCAN_BLKS = (N_NODES + 255) / 256;  // 196
    k_hist<<<(N_EDGES + 255) / 256, 256, 0, stream>>>(edst, counts);
    {
        int* scanscratch = (int*)stage;  // reused before k_stage needs it
        k_scan_blocks<<<SCAN_BLKS, 256, 0, stream>>>(counts, scanscratch, bsum, N_NODES);
        k_scan_sums<<<1, 256, 0, stream>>>(bsum, SCAN_BLKS);
        k_offsets<<<SCAN_BLKS, 256, 0, stream>>>(scanscratch, bsum, offsets, N_NODES);
    }
    k_bcur<<<(N_BUCKETS + 255) / 256, 256, 0, stream>>>(offsets, bcur);
    k_stage<<<(N_EDGES + STAGE_EPB - 1) / STAGE_EPB, STAGE_THREADS, 0, stream>>>(esrc, edst, bcur, stage);
    k_fill2<<<N_BUCKETS, 256, 0, stream>>>(stage, offsets, adj);

    k_cvt<<<(int)(NF / 4 + 255) / 256, 256, 0, stream>>>(x, xbf, (int)(NF / 4));
    k_pack_w<<<10, 256, 0, stream>>>(W1, W2, Wp);

    const int GEMM_BLKS = (N_NODES + 63) / 64;  // 782
    const int POOL_BLKS = (N_NODES + 255) / 256;
    for (int l = 0; l < N_LAYERS; ++l) {
        const ushort* hin = (l == 0) ? xbf : hbf;
        float* st1 = stats + (size_t)(2 * l) * 2048;
        float* st2 = stats + (size_t)(2 * l + 1) * 2048;

        k_agg_gemm1<<<GEMM_BLKS, 256, 0, stream>>>(
            hin, offsets, adj, Wp + (size_t)l * 16384, b1 + l * 128, z1bf, st1);

        k_gemm2<<<GEMM_BLKS, 256, 0, stream>>>(
            z1bf, Wp + (size_t)(5 + l) * 16384, b2 + l * 128,
            bng1 + l * 128, bnb1 + l * 128, st1, z2bf, st2);

        k_apply_pool<<<POOL_BLKS, 256, 0, stream>>>(
            z2bf, st2, bng2 + l * 128, bnb2 + l * 128, batch, hbf, pooled + l * 128);
    }

    k_mlp<<<N_GRAPHS, 128, 0, stream>>>(pooled, fc1W, fc1b, fc2W, fc2b, (float*)d_out);
}

// Round 6
// 604.244 us; speedup vs baseline: 1.1189x; 1.1189x over previous
//
#include <hip/hip_runtime.h>

#define N_NODES 50000
#define N_EDGES 800000
#define N_GRAPHS 256
#define HIDDEN 128
#define N_LAYERS 5
#define OUT_DIM 10
#define BN_EPS 1e-5f

#define BUCKET_SHIFT 7
#define BUCKET_NODES 128
#define N_BUCKETS ((N_NODES + BUCKET_NODES - 1) / BUCKET_NODES)  // 391
#define STAGE_THREADS 1024
#define STAGE_EPB 4096  // edges per block

typedef __bf16 bf16x8 __attribute__((ext_vector_type(8)));
typedef float f32x4 __attribute__((ext_vector_type(4)));

union FragAB {
    bf16x8 v;
    ushort s[8];
    uint4 q;
};

__device__ inline float bf2f(ushort u) {
    union { uint i; float f; } v;
    v.i = ((uint)u) << 16;
    return v.f;
}

__device__ inline float bf2f_lo(uint u) {
    union { uint i; float f; } v;
    v.i = u << 16;
    return v.f;
}

__device__ inline float bf2f_hi(uint u) {
    union { uint i; float f; } v;
    v.i = u & 0xffff0000u;
    return v.f;
}

__device__ inline ushort f2bf(float f) {
    union { float f; uint u; } v;
    v.f = f;
    uint b = v.u;
    uint r = (b + 0x7fffu + ((b >> 16) & 1u)) >> 16;  // RNE
    return (ushort)r;
}

// ---------------- CSR build ----------------

__global__ void k_hist(const int* __restrict__ dst, int* __restrict__ counts) {
    int e = blockIdx.x * blockDim.x + threadIdx.x;
    if (e < N_EDGES) atomicAdd(&counts[dst[e]], 1);
}

__global__ void k_scan_blocks(const int* __restrict__ in, int* __restrict__ out,
                              int* __restrict__ bsum, int n) {
    __shared__ int s[256];
    int i = blockIdx.x * 256 + threadIdx.x;
    int v = (i < n) ? in[i] : 0;
    s[threadIdx.x] = v;
    __syncthreads();
    for (int off = 1; off < 256; off <<= 1) {
        int t = (threadIdx.x >= off) ? s[threadIdx.x - off] : 0;
        __syncthreads();
        s[threadIdx.x] += t;
        __syncthreads();
    }
    if (i < n) out[i] = s[threadIdx.x];
    if (threadIdx.x == 255) bsum[blockIdx.x] = s[255];
}

__global__ void k_scan_sums(int* __restrict__ bsum, int nb) {
    __shared__ int s[256];
    int t = threadIdx.x;
    int v = (t < nb) ? bsum[t] : 0;
    s[t] = v;
    __syncthreads();
    for (int off = 1; off < 256; off <<= 1) {
        int tv = (t >= off) ? s[t - off] : 0;
        __syncthreads();
        s[t] += tv;
        __syncthreads();
    }
    int excl = (t == 0) ? 0 : s[t - 1];
    if (t < nb) bsum[t] = excl;
}

__global__ void k_offsets(const int* __restrict__ scanned, const int* __restrict__ boff,
                          int* __restrict__ offsets, int n) {
    int i = blockIdx.x * 256 + threadIdx.x;
    if (i < n) offsets[i + 1] = scanned[i] + boff[blockIdx.x];
    if (i == 0) offsets[0] = 0;
}

__global__ void k_bcur(const int* __restrict__ offsets, int* __restrict__ bcur) {
    int b = blockIdx.x * 256 + threadIdx.x;
    if (b < N_BUCKETS) bcur[b] = offsets[b * BUCKET_NODES];
}

// pass A: block-local LDS binning into dst-bucket-ordered packed staging.
__global__ __launch_bounds__(STAGE_THREADS) void k_stage(const int* __restrict__ esrc,
                                                         const int* __restrict__ edst,
                                                         int* __restrict__ bcur,
                                                         uint* __restrict__ stage) {
    __shared__ int lcnt[N_BUCKETS];
    __shared__ int lbase[N_BUCKETS];
    int tid = threadIdx.x;
    for (int i = tid; i < N_BUCKETS; i += STAGE_THREADS) lcnt[i] = 0;
    __syncthreads();
    int e0 = blockIdx.x * STAGE_EPB;
    uint pk[4];
    int bk[4];
    bool val[4];
#pragma unroll
    for (int i = 0; i < 4; ++i) {
        int e = e0 + i * STAGE_THREADS + tid;
        val[i] = e < N_EDGES;
        bk[i] = 0;
        pk[i] = 0;
        if (val[i]) {
            int d = edst[e];
            int s = esrc[e];
            bk[i] = d >> BUCKET_SHIFT;
            pk[i] = (uint)s | ((uint)(d & (BUCKET_NODES - 1)) << 16);
            atomicAdd(&lcnt[bk[i]], 1);
        }
    }
    __syncthreads();
    for (int i = tid; i < N_BUCKETS; i += STAGE_THREADS) {
        int c = lcnt[i];
        lbase[i] = c ? atomicAdd(&bcur[i], c) : 0;
        lcnt[i] = 0;
    }
    __syncthreads();
#pragma unroll
    for (int i = 0; i < 4; ++i) {
        if (val[i]) {
            int off = atomicAdd(&lcnt[bk[i]], 1);
            stage[lbase[bk[i]] + off] = pk[i];
        }
    }
}

// pass B: per-bucket local scatter into final adj via LDS cursors
__global__ __launch_bounds__(256) void k_fill2(const uint* __restrict__ stage,
                                               const int* __restrict__ offsets,
                                               ushort* __restrict__ adj) {
    __shared__ int lcur[BUCKET_NODES];
    int bk = blockIdx.x;
    int n0 = bk * BUCKET_NODES;
    int n1 = n0 + BUCKET_NODES;
    if (n1 > N_NODES) n1 = N_NODES;
    int cnt = n1 - n0;
    if ((int)threadIdx.x < cnt) lcur[threadIdx.x] = offsets[n0 + threadIdx.x];
    __syncthreads();
    int s = offsets[n0];
    int e = offsets[n1];
    for (int i = s + threadIdx.x; i < e; i += 256) {
        uint pk = stage[i];
        int dl = pk >> 16;
        int pos = atomicAdd(&lcur[dl], 1);
        adj[pos] = (ushort)(pk & 0xffffu);
    }
}

// ---------------- fp32 -> bf16 convert ----------------

__global__ __launch_bounds__(256) void k_cvt(const float* __restrict__ x,
                                             ushort* __restrict__ xb, int n4) {
    int i = blockIdx.x * 256 + threadIdx.x;
    if (i < n4) {
        float4 v = ((const float4*)x)[i];
        ushort4 o;
        o.x = f2bf(v.x); o.y = f2bf(v.y); o.z = f2bf(v.z); o.w = f2bf(v.w);
        ((ushort4*)xb)[i] = o;
    }
}

// ---------------- pack W into MFMA-B fragment order ----------------

__global__ __launch_bounds__(256) void k_pack_w(const float* __restrict__ W1,
                                                const float* __restrict__ W2,
                                                ushort* __restrict__ Wp) {
    int mat = blockIdx.x;  // 0..9
    const float* src = (mat < 5) ? (W1 + (size_t)mat * 16384)
                                 : (W2 + (size_t)(mat - 5) * 16384);
    ushort* dst = Wp + (size_t)mat * 16384;
    for (int idx = threadIdx.x; idx < 16384; idx += 256) {
        int jj = idx & 7;
        int frag = idx >> 3;
        int lane = frag & 63;
        int cf = frag >> 6;
        int ct = cf >> 2, kc = cf & 3;
        int k = kc * 32 + (lane >> 4) * 8 + jj;
        int c = ct * 16 + (lane & 15);
        dst[idx] = f2bf(src[k * 128 + c]);
    }
}

// ---------------- aggregation: y = h + sum_{u in adj(v)} h[u] ----------------
// One wave per node. 16 lanes (c16) x uint4 cover the 256B row; lane-group
// e = lane>>4 covers edge j+e: 4 edges per wave-instruction, unroll 2 -> 8 in
// flight. Final shfl_xor reduce across groups; 16 lanes store uint4 coalesced.

__global__ __launch_bounds__(256) void k_agg(const ushort* __restrict__ h,
                                             const int* __restrict__ offsets,
                                             const ushort* __restrict__ adj,
                                             ushort* __restrict__ y) {
    int wave = threadIdx.x >> 6;
    int lane = threadIdx.x & 63;
    int e = lane >> 4, c16 = lane & 15;
    int v = blockIdx.x * 4 + wave;
    const uint4* h4 = (const uint4*)h;

    float a0 = 0.f, a1 = 0.f, a2 = 0.f, a3 = 0.f;
    float a4 = 0.f, a5 = 0.f, a6 = 0.f, a7 = 0.f;
    int off = offsets[v];
    int end = offsets[v + 1];
    int j = off;
    for (; j + 8 <= end; j += 8) {
        int u0 = adj[j + e];
        int u1 = adj[j + 4 + e];
        uint4 t0 = h4[(size_t)u0 * 16 + c16];
        uint4 t1 = h4[(size_t)u1 * 16 + c16];
        a0 += bf2f_lo(t0.x); a1 += bf2f_hi(t0.x);
        a2 += bf2f_lo(t0.y); a3 += bf2f_hi(t0.y);
        a4 += bf2f_lo(t0.z); a5 += bf2f_hi(t0.z);
        a6 += bf2f_lo(t0.w); a7 += bf2f_hi(t0.w);
        a0 += bf2f_lo(t1.x); a1 += bf2f_hi(t1.x);
        a2 += bf2f_lo(t1.y); a3 += bf2f_hi(t1.y);
        a4 += bf2f_lo(t1.z); a5 += bf2f_hi(t1.z);
        a6 += bf2f_lo(t1.w); a7 += bf2f_hi(t1.w);
    }
    for (; j < end; j += 4) {
        bool valid = (j + e) < end;
        int u = valid ? adj[j + e] : 0;
        uint4 t = valid ? h4[(size_t)u * 16 + c16] : make_uint4(0, 0, 0, 0);
        a0 += bf2f_lo(t.x); a1 += bf2f_hi(t.x);
        a2 += bf2f_lo(t.y); a3 += bf2f_hi(t.y);
        a4 += bf2f_lo(t.z); a5 += bf2f_hi(t.z);
        a6 += bf2f_lo(t.w); a7 += bf2f_hi(t.w);
    }
    a0 += __shfl_xor(a0, 16, 64); a0 += __shfl_xor(a0, 32, 64);
    a1 += __shfl_xor(a1, 16, 64); a1 += __shfl_xor(a1, 32, 64);
    a2 += __shfl_xor(a2, 16, 64); a2 += __shfl_xor(a2, 32, 64);
    a3 += __shfl_xor(a3, 16, 64); a3 += __shfl_xor(a3, 32, 64);
    a4 += __shfl_xor(a4, 16, 64); a4 += __shfl_xor(a4, 32, 64);
    a5 += __shfl_xor(a5, 16, 64); a5 += __shfl_xor(a5, 32, 64);
    a6 += __shfl_xor(a6, 16, 64); a6 += __shfl_xor(a6, 32, 64);
    a7 += __shfl_xor(a7, 16, 64); a7 += __shfl_xor(a7, 32, 64);
    if (e == 0) {
        uint4 self = h4[(size_t)v * 16 + c16];
        a0 += bf2f_lo(self.x); a1 += bf2f_hi(self.x);
        a2 += bf2f_lo(self.y); a3 += bf2f_hi(self.y);
        a4 += bf2f_lo(self.z); a5 += bf2f_hi(self.z);
        a6 += bf2f_lo(self.w); a7 += bf2f_hi(self.w);
        uint4 pk;
        pk.x = (uint)f2bf(a0) | ((uint)f2bf(a1) << 16);
        pk.y = (uint)f2bf(a2) | ((uint)f2bf(a3) << 16);
        pk.z = (uint)f2bf(a4) | ((uint)f2bf(a5) << 16);
        pk.w = (uint)f2bf(a6) | ((uint)f2bf(a7) << 16);
        ((uint4*)y)[(size_t)v * 16 + c16] = pk;
    }
}

// ---------------- MFMA GEMM with LDS staging + coalesced epilogue + fused stats ----------------

template <bool ACT>
__global__ __launch_bounds__(256) void k_gemm(const ushort* __restrict__ A,
                                              const ushort* __restrict__ Wp,
                                              const float* __restrict__ bias,
                                              const float* __restrict__ g,
                                              const float* __restrict__ b,
                                              const float* __restrict__ statIn,
                                              ushort* __restrict__ Z,
                                              float* __restrict__ statOut) {
    __shared__ ushort As[64 * 128];  // 16KB: row-major, 16B chunks swizzled by (ch+row)&15
    __shared__ float scs[128];
    __shared__ float shs[128];
    __shared__ float redS[4][128];
    __shared__ float redQ[4][128];

    int tid = threadIdx.x;
    int r0 = blockIdx.x * 64;

    if (ACT) {
        if (tid < 128) {
            float s = 0.f, q = 0.f;
#pragma unroll
            for (int sl = 0; sl < 8; ++sl) {
                s += statIn[sl * 256 + tid];
                q += statIn[sl * 256 + 128 + tid];
            }
            float mn = s * (1.f / N_NODES);
            float var = q * (1.f / N_NODES) - mn * mn;
            float sc = g[tid] * rsqrtf(var + BN_EPS);
            scs[tid] = sc;
            shs[tid] = b[tid] - mn * sc;
        }
        __syncthreads();
    }

#pragma unroll
    for (int it = 0; it < 4; ++it) {
        int id = tid + it * 256;
        int row = id >> 4, ch = id & 15;
        int gr = r0 + row;
        uint4 v = make_uint4(0, 0, 0, 0);
        if (gr < N_NODES) {
            v = *(const uint4*)(A + (size_t)gr * 128 + ch * 8);
            if (ACT) {
                FragAB f;
                f.q = v;
                int c0 = ch * 8;
#pragma unroll
                for (int j = 0; j < 8; ++j) {
                    float fv = bf2f(f.s[j]);
                    fv = fmaxf(fv * scs[c0 + j] + shs[c0 + j], 0.f);
                    f.s[j] = f2bf(fv);
                }
                v = f.q;
            }
        }
        *(uint4*)(As + row * 128 + (((ch + row) & 15) * 8)) = v;
    }
    __syncthreads();

    int w = tid >> 6, lane = tid & 63;
    int m = lane & 15, quad = lane >> 4;

    f32x4 acc[8];
#pragma unroll
    for (int ct = 0; ct < 8; ++ct) acc[ct] = (f32x4){0.f, 0.f, 0.f, 0.f};

    const uint4* Wp4 = (const uint4*)Wp;
    int arow = w * 16 + m;

#pragma unroll
    for (int kc = 0; kc < 4; ++kc) {
        FragAB a;
        int ch = kc * 4 + quad;
        a.q = *(const uint4*)(As + arow * 128 + (((ch + arow) & 15) * 8));
#pragma unroll
        for (int ct = 0; ct < 8; ++ct) {
            FragAB bf;
            bf.q = Wp4[(ct * 4 + kc) * 64 + lane];
            acc[ct] = __builtin_amdgcn_mfma_f32_16x16x32_bf16(a.v, bf.v, acc[ct], 0, 0, 0);
        }
    }
    __syncthreads();  // done reading As; reuse as output tile

    int rbase = w * 16 + quad * 4;
#pragma unroll
    for (int ct = 0; ct < 8; ++ct) {
        int c = ct * 16 + m;
        float bc = bias[c];
        float s = 0.f, s2 = 0.f;
#pragma unroll
        for (int i = 0; i < 4; ++i) {
            float val = acc[ct][i] + bc;
            As[(rbase + i) * 128 + c] = f2bf(val);
            if (r0 + rbase + i < N_NODES) {
                s += val;
                s2 += val * val;
            }
        }
        s += __shfl_xor(s, 16, 64);
        s += __shfl_xor(s, 32, 64);
        s2 += __shfl_xor(s2, 16, 64);
        s2 += __shfl_xor(s2, 32, 64);
        if (quad == 0) {
            redS[w][c] = s;
            redQ[w][c] = s2;
        }
    }
    __syncthreads();

#pragma unroll
    for (int it = 0; it < 4; ++it) {
        int id = tid + it * 256;
        int row = id >> 4, seg = id & 15;
        int gr = r0 + row;
        if (gr < N_NODES)
            *(uint4*)(Z + (size_t)gr * 128 + seg * 8) = *(const uint4*)(As + row * 128 + seg * 8);
    }
    if (tid < 128) {
        float s = redS[0][tid] + redS[1][tid] + redS[2][tid] + redS[3][tid];
        float q = redQ[0][tid] + redQ[1][tid] + redQ[2][tid] + redQ[3][tid];
        int slot = (blockIdx.x & 7) * 256;
        atomicAdd(&statOut[slot + tid], s);
        atomicAdd(&statOut[slot + 128 + tid], q);
    }
}

// ---------------- BN2+ReLU + h write + segment pool (wave per 64 rows) ----------------

__global__ __launch_bounds__(256) void k_apply_pool(const ushort* __restrict__ z2,
                                                    const float* __restrict__ statIn,
                                                    const float* __restrict__ g,
                                                    const float* __restrict__ b,
                                                    const int* __restrict__ batch,
                                                    ushort* __restrict__ h,
                                                    float* __restrict__ pooled) {
    int w = threadIdx.x >> 6, lane = threadIdx.x & 63;
    int c0 = lane * 2;
    float s0 = 0.f, q0 = 0.f, s1 = 0.f, q1 = 0.f;
#pragma unroll
    for (int sl = 0; sl < 8; ++sl) {
        s0 += statIn[sl * 256 + c0];
        q0 += statIn[sl * 256 + 128 + c0];
        s1 += statIn[sl * 256 + c0 + 1];
        q1 += statIn[sl * 256 + 128 + c0 + 1];
    }
    float mn0 = s0 * (1.f / N_NODES);
    float var0 = q0 * (1.f / N_NODES) - mn0 * mn0;
    float sc0 = g[c0] * rsqrtf(var0 + BN_EPS);
    float sh0 = b[c0] - mn0 * sc0;
    float mn1 = s1 * (1.f / N_NODES);
    float var1 = q1 * (1.f / N_NODES) - mn1 * mn1;
    float sc1 = g[c0 + 1] * rsqrtf(var1 + BN_EPS);
    float sh1 = b[c0 + 1] - mn1 * sc1;

    int r0 = blockIdx.x * 256 + w * 64;
    int r1 = r0 + 64;
    if (r1 > N_NODES) r1 = N_NODES;
    if (r0 >= N_NODES) return;

    int bidx = r0 + lane;
    int myb = batch[bidx < N_NODES ? bidx : (N_NODES - 1)];

    float a0 = 0.f, a1 = 0.f;
    int curg = -1;
    const uint* z1 = (const uint*)z2;
    uint* h1 = (uint*)h;
    for (int r = r0; r < r1; ++r) {
        uint t = z1[(size_t)r * 64 + lane];
        float v0 = fmaxf(bf2f((ushort)(t & 0xffff)) * sc0 + sh0, 0.f);
        float v1 = fmaxf(bf2f((ushort)(t >> 16)) * sc1 + sh1, 0.f);
        h1[(size_t)r * 64 + lane] = (uint)f2bf(v0) | ((uint)f2bf(v1) << 16);
        int gg = __shfl(myb, r - r0, 64);
        if (gg != curg) {
            if (curg >= 0) {
                atomicAdd(&pooled[(size_t)curg * 640 + c0], a0);
                atomicAdd(&pooled[(size_t)curg * 640 + c0 + 1], a1);
            }
            a0 = 0.f; a1 = 0.f;
            curg = gg;
        }
        a0 += v0;
        a1 += v1;
    }
    if (curg >= 0) {
        atomicAdd(&pooled[(size_t)curg * 640 + c0], a0);
        atomicAdd(&pooled[(size_t)curg * 640 + c0 + 1], a1);
    }
}

// ---------------- final MLP ----------------

__global__ __launch_bounds__(128) void k_mlp(const float* __restrict__ pooled,
                                             const float* __restrict__ fc1W,
                                             const float* __restrict__ fc1b,
                                             const float* __restrict__ fc2W,
                                             const float* __restrict__ fc2b,
                                             float* __restrict__ out) {
    __shared__ float p[640];
    __shared__ float hid[128];
    int g = blockIdx.x;
    int t = threadIdx.x;
    for (int i = t; i < 640; i += 128) p[i] = pooled[(size_t)g * 640 + i];
    __syncthreads();
    float a = fc1b[t];
    for (int k = 0; k < 640; ++k) a += p[k] * fc1W[(size_t)k * 128 + t];
    hid[t] = fmaxf(a, 0.f);
    __syncthreads();
    if (t < OUT_DIM) {
        float o = fc2b[t];
#pragma unroll 8
        for (int c = 0; c < 128; ++c) o += hid[c] * fc2W[(size_t)c * OUT_DIM + t];
        out[(size_t)g * OUT_DIM + t] = o;
    }
}

// ---------------- host ----------------

static inline char* align256(char* p) {
    return (char*)(((uintptr_t)p + 255) & ~(uintptr_t)255);
}

extern "C" void kernel_launch(void* const* d_in, const int* in_sizes, int n_in,
                              void* d_out, int out_size, void* d_ws, size_t ws_size,
                              hipStream_t stream) {
    const float* x    = (const float*)d_in[0];
    const float* W1   = (const float*)d_in[1];
    const float* b1   = (const float*)d_in[2];
    const float* bng1 = (const float*)d_in[3];
    const float* bnb1 = (const float*)d_in[4];
    const float* W2   = (const float*)d_in[5];
    const float* b2   = (const float*)d_in[6];
    const float* bng2 = (const float*)d_in[7];
    const float* bnb2 = (const float*)d_in[8];
    const float* fc1W = (const float*)d_in[9];
    const float* fc1b = (const float*)d_in[10];
    const float* fc2W = (const float*)d_in[11];
    const float* fc2b = (const float*)d_in[12];
    const int* ei     = (const int*)d_in[13];
    const int* batch  = (const int*)d_in[14];
    const int* esrc = ei;
    const int* edst = ei + N_EDGES;

    const size_t NF = (size_t)N_NODES * HIDDEN;
    char* p = (char*)d_ws;
    ushort* ybf  = (ushort*)p; p = align256(p + NF * 2);   // agg out / z2
    ushort* z1bf = (ushort*)p; p = align256(p + NF * 2);
    ushort* hbf  = (ushort*)p; p = align256(p + NF * 2);
    ushort* xbf  = (ushort*)p; p = align256(p + NF * 2);
    ushort* Wp   = (ushort*)p; p = align256(p + (size_t)10 * 16384 * 2);
    float* pooled = (float*)p; p += (size_t)N_GRAPHS * 640 * 4;
    float* stats  = (float*)p; p = align256(p + (size_t)10 * 8 * 256 * 4);
    int* counts   = (int*)p; p = align256(p + (size_t)N_NODES * 4);
    int* offsets  = (int*)p; p = align256(p + (size_t)(N_NODES + 1) * 4);
    int* bcur     = (int*)p; p = align256(p + (size_t)N_BUCKETS * 4);
    int* bsum     = (int*)p; p = align256(p + 256 * 4);
    ushort* adj   = (ushort*)p; p = align256(p + (size_t)N_EDGES * 2);
    uint* stage   = (uint*)p; p = align256(p + (size_t)N_EDGES * 4);

    hipMemsetAsync(counts, 0, (size_t)N_NODES * 4, stream);
    hipMemsetAsync(pooled, 0, ((size_t)N_GRAPHS * 640 + (size_t)10 * 8 * 256) * 4, stream);

    const int SCAN_BLKS = (N_NODES + 255) / 256;  // 196
    k_hist<<<(N_EDGES + 255) / 256, 256, 0, stream>>>(edst, counts);
    {
        int* scanscratch = (int*)stage;  // reused before k_stage needs it
        k_scan_blocks<<<SCAN_BLKS, 256, 0, stream>>>(counts, scanscratch, bsum, N_NODES);
        k_scan_sums<<<1, 256, 0, stream>>>(bsum, SCAN_BLKS);
        k_offsets<<<SCAN_BLKS, 256, 0, stream>>>(scanscratch, bsum, offsets, N_NODES);
    }
    k_bcur<<<(N_BUCKETS + 255) / 256, 256, 0, stream>>>(offsets, bcur);
    k_stage<<<(N_EDGES + STAGE_EPB - 1) / STAGE_EPB, STAGE_THREADS, 0, stream>>>(esrc, edst, bcur, stage);
    k_fill2<<<N_BUCKETS, 256, 0, stream>>>(stage, offsets, adj);

    k_cvt<<<(int)(NF / 4 + 255) / 256, 256, 0, stream>>>(x, xbf, (int)(NF / 4));
    k_pack_w<<<10, 256, 0, stream>>>(W1, W2, Wp);

    const int GEMM_BLKS = (N_NODES + 63) / 64;  // 782
    const int POOL_BLKS = (N_NODES + 255) / 256;
    for (int l = 0; l < N_LAYERS; ++l) {
        const ushort* hin = (l == 0) ? xbf : hbf;
        float* st1 = stats + (size_t)(2 * l) * 2048;
        float* st2 = stats + (size_t)(2 * l + 1) * 2048;

        k_agg<<<N_NODES / 4, 256, 0, stream>>>(hin, offsets, adj, ybf);

        k_gemm<false><<<GEMM_BLKS, 256, 0, stream>>>(
            ybf, Wp + (size_t)l * 16384, b1 + l * 128,
            nullptr, nullptr, nullptr, z1bf, st1);

        k_gemm<true><<<GEMM_BLKS, 256, 0, stream>>>(
            z1bf, Wp + (size_t)(5 + l) * 16384, b2 + l * 128,
            bng1 + l * 128, bnb1 + l * 128, st1, ybf, st2);

        k_apply_pool<<<POOL_BLKS, 256, 0, stream>>>(
            ybf, st2, bng2 + l * 128, bnb2 + l * 128, batch, hbf, pooled + l * 128);
    }

    k_mlp<<<N_GRAPHS, 128, 0, stream>>>(pooled, fc1W, fc1b, fc2W, fc2b, (float*)d_out);
}

// Round 7
// 587.481 us; speedup vs baseline: 1.1509x; 1.0285x over previous
//
#include <hip/hip_runtime.h>

#define N_NODES 50000
#define N_EDGES 800000
#define N_GRAPHS 256
#define HIDDEN 128
#define N_LAYERS 5
#define OUT_DIM 10
#define BN_EPS 1e-5f

#define BUCKET_SHIFT 7
#define BUCKET_NODES 128
#define N_BUCKETS ((N_NODES + BUCKET_NODES - 1) / BUCKET_NODES)  // 391
#define STAGE_THREADS 1024
#define STAGE_EPB 4096  // edges per block

typedef __bf16 bf16x8 __attribute__((ext_vector_type(8)));
typedef float f32x4 __attribute__((ext_vector_type(4)));

union FragAB {
    bf16x8 v;
    ushort s[8];
    uint4 q;
};

__device__ inline float bf2f(ushort u) {
    union { uint i; float f; } v;
    v.i = ((uint)u) << 16;
    return v.f;
}

__device__ inline float bf2f_lo(uint u) {
    union { uint i; float f; } v;
    v.i = u << 16;
    return v.f;
}

__device__ inline float bf2f_hi(uint u) {
    union { uint i; float f; } v;
    v.i = u & 0xffff0000u;
    return v.f;
}

__device__ inline ushort f2bf(float f) {
    union { float f; uint u; } v;
    v.f = f;
    uint b = v.u;
    uint r = (b + 0x7fffu + ((b >> 16) & 1u)) >> 16;  // RNE
    return (ushort)r;
}

// ---------------- CSR build ----------------

__global__ void k_hist(const int* __restrict__ dst, int* __restrict__ counts) {
    int e = blockIdx.x * blockDim.x + threadIdx.x;
    if (e < N_EDGES) atomicAdd(&counts[dst[e]], 1);
}

__global__ void k_scan_blocks(const int* __restrict__ in, int* __restrict__ out,
                              int* __restrict__ bsum, int n) {
    __shared__ int s[256];
    int i = blockIdx.x * 256 + threadIdx.x;
    int v = (i < n) ? in[i] : 0;
    s[threadIdx.x] = v;
    __syncthreads();
    for (int off = 1; off < 256; off <<= 1) {
        int t = (threadIdx.x >= off) ? s[threadIdx.x - off] : 0;
        __syncthreads();
        s[threadIdx.x] += t;
        __syncthreads();
    }
    if (i < n) out[i] = s[threadIdx.x];
    if (threadIdx.x == 255) bsum[blockIdx.x] = s[255];
}

__global__ void k_scan_sums(int* __restrict__ bsum, int nb) {
    __shared__ int s[256];
    int t = threadIdx.x;
    int v = (t < nb) ? bsum[t] : 0;
    s[t] = v;
    __syncthreads();
    for (int off = 1; off < 256; off <<= 1) {
        int tv = (t >= off) ? s[t - off] : 0;
        __syncthreads();
        s[t] += tv;
        __syncthreads();
    }
    int excl = (t == 0) ? 0 : s[t - 1];
    if (t < nb) bsum[t] = excl;
}

__global__ void k_offsets(const int* __restrict__ scanned, const int* __restrict__ boff,
                          int* __restrict__ offsets, int n) {
    int i = blockIdx.x * 256 + threadIdx.x;
    if (i < n) offsets[i + 1] = scanned[i] + boff[blockIdx.x];
    if (i == 0) offsets[0] = 0;
}

__global__ void k_bcur(const int* __restrict__ offsets, int* __restrict__ bcur) {
    int b = blockIdx.x * 256 + threadIdx.x;
    if (b < N_BUCKETS) bcur[b] = offsets[b * BUCKET_NODES];
}

// pass A: block-local LDS binning into dst-bucket-ordered packed staging.
__global__ __launch_bounds__(STAGE_THREADS) void k_stage(const int* __restrict__ esrc,
                                                         const int* __restrict__ edst,
                                                         int* __restrict__ bcur,
                                                         uint* __restrict__ stage) {
    __shared__ int lcnt[N_BUCKETS];
    __shared__ int lbase[N_BUCKETS];
    int tid = threadIdx.x;
    for (int i = tid; i < N_BUCKETS; i += STAGE_THREADS) lcnt[i] = 0;
    __syncthreads();
    int e0 = blockIdx.x * STAGE_EPB;
    uint pk[4];
    int bk[4];
    bool val[4];
#pragma unroll
    for (int i = 0; i < 4; ++i) {
        int e = e0 + i * STAGE_THREADS + tid;
        val[i] = e < N_EDGES;
        bk[i] = 0;
        pk[i] = 0;
        if (val[i]) {
            int d = edst[e];
            int s = esrc[e];
            bk[i] = d >> BUCKET_SHIFT;
            pk[i] = (uint)s | ((uint)(d & (BUCKET_NODES - 1)) << 16);
            atomicAdd(&lcnt[bk[i]], 1);
        }
    }
    __syncthreads();
    for (int i = tid; i < N_BUCKETS; i += STAGE_THREADS) {
        int c = lcnt[i];
        lbase[i] = c ? atomicAdd(&bcur[i], c) : 0;
        lcnt[i] = 0;
    }
    __syncthreads();
#pragma unroll
    for (int i = 0; i < 4; ++i) {
        if (val[i]) {
            int off = atomicAdd(&lcnt[bk[i]], 1);
            stage[lbase[bk[i]] + off] = pk[i];
        }
    }
}

// pass B: per-bucket local scatter into final adj via LDS cursors
__global__ __launch_bounds__(256) void k_fill2(const uint* __restrict__ stage,
                                               const int* __restrict__ offsets,
                                               ushort* __restrict__ adj) {
    __shared__ int lcur[BUCKET_NODES];
    int bk = blockIdx.x;
    int n0 = bk * BUCKET_NODES;
    int n1 = n0 + BUCKET_NODES;
    if (n1 > N_NODES) n1 = N_NODES;
    int cnt = n1 - n0;
    if ((int)threadIdx.x < cnt) lcur[threadIdx.x] = offsets[n0 + threadIdx.x];
    __syncthreads();
    int s = offsets[n0];
    int e = offsets[n1];
    for (int i = s + threadIdx.x; i < e; i += 256) {
        uint pk = stage[i];
        int dl = pk >> 16;
        int pos = atomicAdd(&lcur[dl], 1);
        adj[pos] = (ushort)(pk & 0xffffu);
    }
}

// ---------------- fp32 -> bf16 convert ----------------

__global__ __launch_bounds__(256) void k_cvt(const float* __restrict__ x,
                                             ushort* __restrict__ xb, int n4) {
    int i = blockIdx.x * 256 + threadIdx.x;
    if (i < n4) {
        float4 v = ((const float4*)x)[i];
        ushort4 o;
        o.x = f2bf(v.x); o.y = f2bf(v.y); o.z = f2bf(v.z); o.w = f2bf(v.w);
        ((ushort4*)xb)[i] = o;
    }
}

// ---------------- pack W into MFMA-B fragment order ----------------
// B-frag ct covers global col c = (lane&15)*8 + ct  (so each lane's 8 acc
// cover 8 consecutive global columns -> coalesced uint4 epilogue store)

__global__ __launch_bounds__(256) void k_pack_w(const float* __restrict__ W1,
                                                const float* __restrict__ W2,
                                                ushort* __restrict__ Wp) {
    int mat = blockIdx.x;  // 0..9
    const float* src = (mat < 5) ? (W1 + (size_t)mat * 16384)
                                 : (W2 + (size_t)(mat - 5) * 16384);
    ushort* dst = Wp + (size_t)mat * 16384;
    for (int idx = threadIdx.x; idx < 16384; idx += 256) {
        int jj = idx & 7;
        int frag = idx >> 3;
        int lane = frag & 63;
        int cf = frag >> 6;
        int ct = cf >> 2, kc = cf & 3;
        int k = kc * 32 + (lane >> 4) * 8 + jj;
        int c = (lane & 15) * 8 + ct;
        dst[idx] = f2bf(src[k * 128 + c]);
    }
}

// ---------------- aggregation: y = h + sum_{u in adj(v)} h[u] ----------------
// One wave per node. 16 lanes (c16) x uint4 cover the 256B row; lane-group
// e = lane>>4 covers edge j+e. 16-edge unroll -> 4 gather loads in flight/lane.

__global__ __launch_bounds__(256) void k_agg(const ushort* __restrict__ h,
                                             const int* __restrict__ offsets,
                                             const ushort* __restrict__ adj,
                                             ushort* __restrict__ y) {
    int wave = threadIdx.x >> 6;
    int lane = threadIdx.x & 63;
    int e = lane >> 4, c16 = lane & 15;
    int v = blockIdx.x * 4 + wave;
    const uint4* h4 = (const uint4*)h;

    float a0 = 0.f, a1 = 0.f, a2 = 0.f, a3 = 0.f;
    float a4 = 0.f, a5 = 0.f, a6 = 0.f, a7 = 0.f;
    int off = offsets[v];
    int end = offsets[v + 1];
    int j = off;
    for (; j + 16 <= end; j += 16) {
        int u0 = adj[j + e];
        int u1 = adj[j + 4 + e];
        int u2 = adj[j + 8 + e];
        int u3 = adj[j + 12 + e];
        uint4 t0 = h4[(size_t)u0 * 16 + c16];
        uint4 t1 = h4[(size_t)u1 * 16 + c16];
        uint4 t2 = h4[(size_t)u2 * 16 + c16];
        uint4 t3 = h4[(size_t)u3 * 16 + c16];
        a0 += bf2f_lo(t0.x); a1 += bf2f_hi(t0.x);
        a2 += bf2f_lo(t0.y); a3 += bf2f_hi(t0.y);
        a4 += bf2f_lo(t0.z); a5 += bf2f_hi(t0.z);
        a6 += bf2f_lo(t0.w); a7 += bf2f_hi(t0.w);
        a0 += bf2f_lo(t1.x); a1 += bf2f_hi(t1.x);
        a2 += bf2f_lo(t1.y); a3 += bf2f_hi(t1.y);
        a4 += bf2f_lo(t1.z); a5 += bf2f_hi(t1.z);
        a6 += bf2f_lo(t1.w); a7 += bf2f_hi(t1.w);
        a0 += bf2f_lo(t2.x); a1 += bf2f_hi(t2.x);
        a2 += bf2f_lo(t2.y); a3 += bf2f_hi(t2.y);
        a4 += bf2f_lo(t2.z); a5 += bf2f_hi(t2.z);
        a6 += bf2f_lo(t2.w); a7 += bf2f_hi(t2.w);
        a0 += bf2f_lo(t3.x); a1 += bf2f_hi(t3.x);
        a2 += bf2f_lo(t3.y); a3 += bf2f_hi(t3.y);
        a4 += bf2f_lo(t3.z); a5 += bf2f_hi(t3.z);
        a6 += bf2f_lo(t3.w); a7 += bf2f_hi(t3.w);
    }
    for (; j < end; j += 4) {
        bool valid = (j + e) < end;
        int u = valid ? adj[j + e] : 0;
        uint4 t = valid ? h4[(size_t)u * 16 + c16] : make_uint4(0, 0, 0, 0);
        a0 += bf2f_lo(t.x); a1 += bf2f_hi(t.x);
        a2 += bf2f_lo(t.y); a3 += bf2f_hi(t.y);
        a4 += bf2f_lo(t.z); a5 += bf2f_hi(t.z);
        a6 += bf2f_lo(t.w); a7 += bf2f_hi(t.w);
    }
    a0 += __shfl_xor(a0, 16, 64); a0 += __shfl_xor(a0, 32, 64);
    a1 += __shfl_xor(a1, 16, 64); a1 += __shfl_xor(a1, 32, 64);
    a2 += __shfl_xor(a2, 16, 64); a2 += __shfl_xor(a2, 32, 64);
    a3 += __shfl_xor(a3, 16, 64); a3 += __shfl_xor(a3, 32, 64);
    a4 += __shfl_xor(a4, 16, 64); a4 += __shfl_xor(a4, 32, 64);
    a5 += __shfl_xor(a5, 16, 64); a5 += __shfl_xor(a5, 32, 64);
    a6 += __shfl_xor(a6, 16, 64); a6 += __shfl_xor(a6, 32, 64);
    a7 += __shfl_xor(a7, 16, 64); a7 += __shfl_xor(a7, 32, 64);
    if (e == 0) {
        uint4 self = h4[(size_t)v * 16 + c16];
        a0 += bf2f_lo(self.x); a1 += bf2f_hi(self.x);
        a2 += bf2f_lo(self.y); a3 += bf2f_hi(self.y);
        a4 += bf2f_lo(self.z); a5 += bf2f_hi(self.z);
        a6 += bf2f_lo(self.w); a7 += bf2f_hi(self.w);
        uint4 pk;
        pk.x = (uint)f2bf(a0) | ((uint)f2bf(a1) << 16);
        pk.y = (uint)f2bf(a2) | ((uint)f2bf(a3) << 16);
        pk.z = (uint)f2bf(a4) | ((uint)f2bf(a5) << 16);
        pk.w = (uint)f2bf(a6) | ((uint)f2bf(a7) << 16);
        ((uint4*)y)[(size_t)v * 16 + c16] = pk;
    }
}

// ---------------- MFMA GEMM: direct global frag loads + direct coalesced store ----------------
// 64 rows per 256-thread block (wave w: rows r0+w*16..+15). No data LDS.
// Lane (m,quad): A-frag rows r0+w*16+m, output rows r0+w*16+quad*4+i,
// output cols m*8..m*8+7 (via new W packing). Fused column stats.

template <bool ACT>
__global__ __launch_bounds__(256) void k_gemm(const ushort* __restrict__ A,
                                              const ushort* __restrict__ Wp,
                                              const float* __restrict__ bias,
                                              const float* __restrict__ g,
                                              const float* __restrict__ b,
                                              const float* __restrict__ statIn,
                                              ushort* __restrict__ Z,
                                              float* __restrict__ statOut) {
    __shared__ float scs[128];
    __shared__ float shs[128];
    __shared__ float redS[4][128];
    __shared__ float redQ[4][128];

    int tid = threadIdx.x;
    int w = tid >> 6, lane = tid & 63;
    int m = lane & 15, quad = lane >> 4;
    int r0 = blockIdx.x * 64;

    if (ACT) {
        if (tid < 128) {
            float s = 0.f, q = 0.f;
#pragma unroll
            for (int sl = 0; sl < 8; ++sl) {
                s += statIn[sl * 256 + tid];
                q += statIn[sl * 256 + 128 + tid];
            }
            float mn = s * (1.f / N_NODES);
            float var = q * (1.f / N_NODES) - mn * mn;
            float sc = g[tid] * rsqrtf(var + BN_EPS);
            scs[tid] = sc;
            shs[tid] = b[tid] - mn * sc;
        }
        __syncthreads();
    }

    int arow = r0 + w * 16 + m;
    if (arow >= N_NODES) arow = N_NODES - 1;  // clamp (stats/store exclude)

    f32x4 acc[8];
#pragma unroll
    for (int ct = 0; ct < 8; ++ct) acc[ct] = (f32x4){0.f, 0.f, 0.f, 0.f};

    const uint4* Wp4 = (const uint4*)Wp;

#pragma unroll
    for (int kc = 0; kc < 4; ++kc) {
        FragAB a;
        a.q = *(const uint4*)(A + (size_t)arow * 128 + kc * 32 + quad * 8);
        if (ACT) {
            int k0 = kc * 32 + quad * 8;
#pragma unroll
            for (int jj = 0; jj < 8; ++jj) {
                float fv = bf2f(a.s[jj]);
                fv = fmaxf(fv * scs[k0 + jj] + shs[k0 + jj], 0.f);
                a.s[jj] = f2bf(fv);
            }
        }
#pragma unroll
        for (int ct = 0; ct < 8; ++ct) {
            FragAB bf;
            bf.q = Wp4[(ct * 4 + kc) * 64 + lane];
            acc[ct] = __builtin_amdgcn_mfma_f32_16x16x32_bf16(a.v, bf.v, acc[ct], 0, 0, 0);
        }
    }

    // epilogue: bias + direct coalesced store + stats
    int rbase = r0 + w * 16 + quad * 4;
    float bc[8];
#pragma unroll
    for (int ct = 0; ct < 8; ++ct) bc[ct] = bias[m * 8 + ct];

    float st[8], sq[8];
#pragma unroll
    for (int ct = 0; ct < 8; ++ct) { st[ct] = 0.f; sq[ct] = 0.f; }

#pragma unroll
    for (int i = 0; i < 4; ++i) {
        int row = rbase + i;
        if (row < N_NODES) {
            float v[8];
#pragma unroll
            for (int ct = 0; ct < 8; ++ct) {
                v[ct] = acc[ct][i] + bc[ct];
                st[ct] += v[ct];
                sq[ct] += v[ct] * v[ct];
            }
            uint4 pk;
            pk.x = (uint)f2bf(v[0]) | ((uint)f2bf(v[1]) << 16);
            pk.y = (uint)f2bf(v[2]) | ((uint)f2bf(v[3]) << 16);
            pk.z = (uint)f2bf(v[4]) | ((uint)f2bf(v[5]) << 16);
            pk.w = (uint)f2bf(v[6]) | ((uint)f2bf(v[7]) << 16);
            *(uint4*)(Z + (size_t)row * 128 + m * 8) = pk;
        }
    }
#pragma unroll
    for (int ct = 0; ct < 8; ++ct) {
        st[ct] += __shfl_xor(st[ct], 16, 64);
        st[ct] += __shfl_xor(st[ct], 32, 64);
        sq[ct] += __shfl_xor(sq[ct], 16, 64);
        sq[ct] += __shfl_xor(sq[ct], 32, 64);
    }
    if (quad == 0) {
#pragma unroll
        for (int ct = 0; ct < 8; ++ct) {
            redS[w][m * 8 + ct] = st[ct];
            redQ[w][m * 8 + ct] = sq[ct];
        }
    }
    __syncthreads();
    if (tid < 128) {
        float s = redS[0][tid] + redS[1][tid] + redS[2][tid] + redS[3][tid];
        float q = redQ[0][tid] + redQ[1][tid] + redQ[2][tid] + redQ[3][tid];
        int slot = (blockIdx.x & 7) * 256;
        atomicAdd(&statOut[slot + tid], s);
        atomicAdd(&statOut[slot + 128 + tid], q);
    }
}

// ---------------- BN2+ReLU + h write + segment pool (wave per 64 rows) ----------------

__global__ __launch_bounds__(256) void k_apply_pool(const ushort* __restrict__ z2,
                                                    const float* __restrict__ statIn,
                                                    const float* __restrict__ g,
                                                    const float* __restrict__ b,
                                                    const int* __restrict__ batch,
                                                    ushort* __restrict__ h,
                                                    float* __restrict__ pooled) {
    int w = threadIdx.x >> 6, lane = threadIdx.x & 63;
    int c0 = lane * 2;
    float s0 = 0.f, q0 = 0.f, s1 = 0.f, q1 = 0.f;
#pragma unroll
    for (int sl = 0; sl < 8; ++sl) {
        s0 += statIn[sl * 256 + c0];
        q0 += statIn[sl * 256 + 128 + c0];
        s1 += statIn[sl * 256 + c0 + 1];
        q1 += statIn[sl * 256 + 128 + c0 + 1];
    }
    float mn0 = s0 * (1.f / N_NODES);
    float var0 = q0 * (1.f / N_NODES) - mn0 * mn0;
    float sc0 = g[c0] * rsqrtf(var0 + BN_EPS);
    float sh0 = b[c0] - mn0 * sc0;
    float mn1 = s1 * (1.f / N_NODES);
    float var1 = q1 * (1.f / N_NODES) - mn1 * mn1;
    float sc1 = g[c0 + 1] * rsqrtf(var1 + BN_EPS);
    float sh1 = b[c0 + 1] - mn1 * sc1;

    int r0 = blockIdx.x * 256 + w * 64;
    int r1 = r0 + 64;
    if (r1 > N_NODES) r1 = N_NODES;
    if (r0 >= N_NODES) return;

    int bidx = r0 + lane;
    int myb = batch[bidx < N_NODES ? bidx : (N_NODES - 1)];

    float a0 = 0.f, a1 = 0.f;
    int curg = -1;
    const uint* z1 = (const uint*)z2;
    uint* h1 = (uint*)h;
    for (int r = r0; r < r1; ++r) {
        uint t = z1[(size_t)r * 64 + lane];
        float v0 = fmaxf(bf2f((ushort)(t & 0xffff)) * sc0 + sh0, 0.f);
        float v1 = fmaxf(bf2f((ushort)(t >> 16)) * sc1 + sh1, 0.f);
        h1[(size_t)r * 64 + lane] = (uint)f2bf(v0) | ((uint)f2bf(v1) << 16);
        int gg = __shfl(myb, r - r0, 64);
        if (gg != curg) {
            if (curg >= 0) {
                atomicAdd(&pooled[(size_t)curg * 640 + c0], a0);
                atomicAdd(&pooled[(size_t)curg * 640 + c0 + 1], a1);
            }
            a0 = 0.f; a1 = 0.f;
            curg = gg;
        }
        a0 += v0;
        a1 += v1;
    }
    if (curg >= 0) {
        atomicAdd(&pooled[(size_t)curg * 640 + c0], a0);
        atomicAdd(&pooled[(size_t)curg * 640 + c0 + 1], a1);
    }
}

// ---------------- final MLP ----------------

__global__ __launch_bounds__(128) void k_mlp(const float* __restrict__ pooled,
                                             const float* __restrict__ fc1W,
                                             const float* __restrict__ fc1b,
                                             const float* __restrict__ fc2W,
                                             const float* __restrict__ fc2b,
                                             float* __restrict__ out) {
    __shared__ float p[640];
    __shared__ float hid[128];
    int g = blockIdx.x;
    int t = threadIdx.x;
    for (int i = t; i < 640; i += 128) p[i] = pooled[(size_t)g * 640 + i];
    __syncthreads();
    float a = fc1b[t];
    for (int k = 0; k < 640; ++k) a += p[k] * fc1W[(size_t)k * 128 + t];
    hid[t] = fmaxf(a, 0.f);
    __syncthreads();
    if (t < OUT_DIM) {
        float o = fc2b[t];
#pragma unroll 8
        for (int c = 0; c < 128; ++c) o += hid[c] * fc2W[(size_t)c * OUT_DIM + t];
        out[(size_t)g * OUT_DIM + t] = o;
    }
}

// ---------------- host ----------------

static inline char* align256(char* p) {
    return (char*)(((uintptr_t)p + 255) & ~(uintptr_t)255);
}

extern "C" void kernel_launch(void* const* d_in, const int* in_sizes, int n_in,
                              void* d_out, int out_size, void* d_ws, size_t ws_size,
                              hipStream_t stream) {
    const float* x    = (const float*)d_in[0];
    const float* W1   = (const float*)d_in[1];
    const float* b1   = (const float*)d_in[2];
    const float* bng1 = (const float*)d_in[3];
    const float* bnb1 = (const float*)d_in[4];
    const float* W2   = (const float*)d_in[5];
    const float* b2   = (const float*)d_in[6];
    const float* bng2 = (const float*)d_in[7];
    const float* bnb2 = (const float*)d_in[8];
    const float* fc1W = (const float*)d_in[9];
    const float* fc1b = (const float*)d_in[10];
    const float* fc2W = (const float*)d_in[11];
    const float* fc2b = (const float*)d_in[12];
    const int* ei     = (const int*)d_in[13];
    const int* batch  = (const int*)d_in[14];
    const int* esrc = ei;
    const int* edst = ei + N_EDGES;

    const size_t NF = (size_t)N_NODES * HIDDEN;
    char* p = (char*)d_ws;
    ushort* ybf  = (ushort*)p; p = align256(p + NF * 2);   // agg out / z2
    ushort* z1bf = (ushort*)p; p = align256(p + NF * 2);
    ushort* hbf  = (ushort*)p; p = align256(p + NF * 2);
    ushort* xbf  = (ushort*)p; p = align256(p + NF * 2);
    ushort* Wp   = (ushort*)p; p = align256(p + (size_t)10 * 16384 * 2);
    float* pooled = (float*)p; p += (size_t)N_GRAPHS * 640 * 4;
    float* stats  = (float*)p; p = align256(p + (size_t)10 * 8 * 256 * 4);
    int* counts   = (int*)p; p = align256(p + (size_t)N_NODES * 4);
    int* offsets  = (int*)p; p = align256(p + (size_t)(N_NODES + 1) * 4);
    int* bcur     = (int*)p; p = align256(p + (size_t)N_BUCKETS * 4);
    int* bsum     = (int*)p; p = align256(p + 256 * 4);
    ushort* adj   = (ushort*)p; p = align256(p + (size_t)N_EDGES * 2);
    uint* stage   = (uint*)p; p = align256(p + (size_t)N_EDGES * 4);

    hipMemsetAsync(counts, 0, (size_t)N_NODES * 4, stream);
    hipMemsetAsync(pooled, 0, ((size_t)N_GRAPHS * 640 + (size_t)10 * 8 * 256) * 4, stream);

    const int SCAN_BLKS = (N_NODES + 255) / 256;  // 196
    k_hist<<<(N_EDGES + 255) / 256, 256, 0, stream>>>(edst, counts);
    {
        int* scanscratch = (int*)stage;  // reused before k_stage needs it
        k_scan_blocks<<<SCAN_BLKS, 256, 0, stream>>>(counts, scanscratch, bsum, N_NODES);
        k_scan_sums<<<1, 256, 0, stream>>>(bsum, SCAN_BLKS);
        k_offsets<<<SCAN_BLKS, 256, 0, stream>>>(scanscratch, bsum, offsets, N_NODES);
    }
    k_bcur<<<(N_BUCKETS + 255) / 256, 256, 0, stream>>>(offsets, bcur);
    k_stage<<<(N_EDGES + STAGE_EPB - 1) / STAGE_EPB, STAGE_THREADS, 0, stream>>>(esrc, edst, bcur, stage);
    k_fill2<<<N_BUCKETS, 256, 0, stream>>>(stage, offsets, adj);

    k_cvt<<<(int)(NF / 4 + 255) / 256, 256, 0, stream>>>(x, xbf, (int)(NF / 4));
    k_pack_w<<<10, 256, 0, stream>>>(W1, W2, Wp);

    const int GEMM_BLKS = (N_NODES + 63) / 64;  // 782
    const int POOL_BLKS = (N_NODES + 255) / 256;
    for (int l = 0; l < N_LAYERS; ++l) {
        const ushort* hin = (l == 0) ? xbf : hbf;
        float* st1 = stats + (size_t)(2 * l) * 2048;
        float* st2 = stats + (size_t)(2 * l + 1) * 2048;

        k_agg<<<N_NODES / 4, 256, 0, stream>>>(hin, offsets, adj, ybf);

        k_gemm<false><<<GEMM_BLKS, 256, 0, stream>>>(
            ybf, Wp + (size_t)l * 16384, b1 + l * 128,
            nullptr, nullptr, nullptr, z1bf, st1);

        k_gemm<true><<<GEMM_BLKS, 256, 0, stream>>>(
            z1bf, Wp + (size_t)(5 + l) * 16384, b2 + l * 128,
            bng1 + l * 128, bnb1 + l * 128, st1, ybf, st2);

        k_apply_pool<<<POOL_BLKS, 256, 0, stream>>>(
            ybf, st2, bng2 + l * 128, bnb2 + l * 128, batch, hbf, pooled + l * 128);
    }

    k_mlp<<<N_GRAPHS, 128, 0, stream>>>(pooled, fc1W, fc1b, fc2W, fc2b, (float*)d_out);
}